// Round 1
// baseline (387.458 us; speedup 1.0000x reference)
//
#include <hip/hip_runtime.h>
#include <hip/hip_bf16.h>
#include <math.h>

#define N_NODES 6144
#define NFEAT 512
#define NHID 256
#define NHEADS 4
#define DHEAD 64
#define NEMBED 128
#define LRELU_ALPHA 0.2f

// ---------------------------------------------------------------------------
// Kernel 1: Wh[h][n][d] = sum_f x[n][f] * W[h][f][d]
// Tiled fp32 GEMM: 64x64 output tile per block (block cols = one head's full d
// range since tile width == DHEAD == 64), 256 threads, 4x4 micro-tile, K-tile 16.
// ---------------------------------------------------------------------------
__global__ __launch_bounds__(256) void wh_gemm(const float* __restrict__ x,
                                               const float* __restrict__ W,
                                               float* __restrict__ Wh) {
    __shared__ float As[64][16];
    __shared__ float Bs[16][64];
    const int tid = threadIdx.x;
    const int tx = tid & 15;        // 0..15 -> 4 cols each
    const int ty = tid >> 4;        // 0..15 -> 4 rows each
    const int row0 = blockIdx.x * 64;
    const int h = blockIdx.y;       // head = column block (64 cols = DHEAD)
    const float* Bp = W + (size_t)h * NFEAT * DHEAD;

    float acc[4][4] = {};

    for (int k0 = 0; k0 < NFEAT; k0 += 16) {
        // load A tile: 64 rows x 16 k
        {
            const int r = tid >> 2, kq = tid & 3;
            const float4 v = *(const float4*)(x + (size_t)(row0 + r) * NFEAT + k0 + kq * 4);
            *(float4*)&As[r][kq * 4] = v;
        }
        // load B tile: 16 k x 64 cols (contiguous in d)
        {
            const int kk = tid >> 4, cq = tid & 15;
            const float4 v = *(const float4*)(Bp + (size_t)(k0 + kk) * DHEAD + cq * 4);
            *(float4*)&Bs[kk][cq * 4] = v;
        }
        __syncthreads();
#pragma unroll
        for (int kk = 0; kk < 16; kk++) {
            float a[4], b[4];
#pragma unroll
            for (int i = 0; i < 4; i++) a[i] = As[ty * 4 + i][kk];
#pragma unroll
            for (int j = 0; j < 4; j++) b[j] = Bs[kk][tx * 4 + j];
#pragma unroll
            for (int i = 0; i < 4; i++)
#pragma unroll
                for (int j = 0; j < 4; j++) acc[i][j] += a[i] * b[j];
        }
        __syncthreads();
    }
    // store Wh[(h*N + row)*64 + col]
#pragma unroll
    for (int i = 0; i < 4; i++) {
        const int row = row0 + ty * 4 + i;
        float4 v = make_float4(acc[i][0], acc[i][1], acc[i][2], acc[i][3]);
        *(float4*)(Wh + ((size_t)h * N_NODES + row) * DHEAD + tx * 4) = v;
    }
}

// ---------------------------------------------------------------------------
// Kernel 2: s[h][n] = dot(Wh[h][n][:], a_src[h][:]); t likewise with a_dst.
// One block per node, one wave (64 lanes) per head.
// ---------------------------------------------------------------------------
__global__ __launch_bounds__(256) void st_kernel(const float* __restrict__ Wh,
                                                 const float* __restrict__ a_src,
                                                 const float* __restrict__ a_dst,
                                                 float* __restrict__ s_arr,
                                                 float* __restrict__ t_arr) {
    const int n = blockIdx.x;
    const int h = threadIdx.x >> 6;
    const int lane = threadIdx.x & 63;
    const float wh = Wh[((size_t)h * N_NODES + n) * DHEAD + lane];
    float ps = wh * a_src[h * DHEAD + lane];
    float pt = wh * a_dst[h * DHEAD + lane];
#pragma unroll
    for (int off = 32; off > 0; off >>= 1) {
        ps += __shfl_down(ps, off);
        pt += __shfl_down(pt, off);
    }
    if (lane == 0) {
        s_arr[h * N_NODES + n] = ps;
        t_arr[h * N_NODES + n] = pt;
    }
}

// ---------------------------------------------------------------------------
// Kernel 3: per-row sparse attention + aggregation + ELU.
// Block = one destination node i, 256 threads = 4 waves; wave h owns head h,
// lane d owns output dim d. Scan adj row -> compact neighbor list in LDS ->
// online softmax over neighbors, accumulate p * Wh[h][j][d].
// ---------------------------------------------------------------------------
__global__ __launch_bounds__(256) void attn_agg(const int* __restrict__ adj,
                                                const float* __restrict__ Wh,
                                                const float* __restrict__ s_arr,
                                                const float* __restrict__ t_arr,
                                                float* __restrict__ hcat) {
    __shared__ int nbr[N_NODES];
    __shared__ int cnt;
    const int i = blockIdx.x;
    const int tid = threadIdx.x;
    if (tid == 0) cnt = 0;
    __syncthreads();

    const int* arow = adj + (size_t)i * N_NODES;
    for (int j = tid; j < N_NODES; j += 256) {
        if (arow[j] > 0) {
            int p = atomicAdd(&cnt, 1);
            nbr[p] = j;
        }
    }
    __syncthreads();
    const int c = cnt;

    const int h = tid >> 6;
    const int lane = tid & 63;
    const float s_h = s_arr[h * N_NODES + i];
    const float* tp = t_arr + (size_t)h * N_NODES;
    const float* whp = Wh + (size_t)h * N_NODES * DHEAD;

    float m = -INFINITY, l = 0.0f, acc = 0.0f;
    if (c > 0) {
        for (int k = 0; k < c; k++) {
            const int j = nbr[k];
            float e = s_h + tp[j];
            e = e >= 0.0f ? e : LRELU_ALPHA * e;
            const float m_new = fmaxf(m, e);
            const float scale = expf(m - m_new);   // first iter: exp(-inf)=0
            const float p = expf(e - m_new);
            l = l * scale + p;
            acc = acc * scale + p * whp[(size_t)j * DHEAD + lane];
            m = m_new;
        }
    } else {
        // all logits equal NEG_INF -> softmax uniform over all nodes
        for (int j = 0; j < N_NODES; j++) acc += whp[(size_t)j * DHEAD + lane];
        l = (float)N_NODES;
    }
    float hv = acc / l;
    hv = hv > 0.0f ? hv : expm1f(hv);              // ELU
    hcat[(size_t)i * NHID + h * DHEAD + lane] = hv;
}

// ---------------------------------------------------------------------------
// Kernel 4: out[n][m] = elu(dot(hcat[n][:], lin_w[m][:]) + lin_b[m])
// 64x64 tile per block, grid (96, 2).
// ---------------------------------------------------------------------------
__global__ __launch_bounds__(256) void out_gemm(const float* __restrict__ hcat,
                                                const float* __restrict__ lin_w,
                                                const float* __restrict__ lin_b,
                                                float* __restrict__ out) {
    __shared__ float As[64][16];
    __shared__ float Bs[16][64];
    const int tid = threadIdx.x;
    const int tx = tid & 15;
    const int ty = tid >> 4;
    const int row0 = blockIdx.x * 64;
    const int c0 = blockIdx.y * 64;

    float acc[4][4] = {};

    for (int k0 = 0; k0 < NHID; k0 += 16) {
        {
            const int r = tid >> 2, kq = tid & 3;
            const float4 v = *(const float4*)(hcat + (size_t)(row0 + r) * NHID + k0 + kq * 4);
            *(float4*)&As[r][kq * 4] = v;
        }
        {
            // Bs[kk][cc] = lin_w[(c0+cc)*NHID + k0+kk]  (transpose on store)
            const int cc = tid & 63, kq = tid >> 6;   // kq 0..3
            const float4 v = *(const float4*)(lin_w + (size_t)(c0 + cc) * NHID + k0 + kq * 4);
            Bs[kq * 4 + 0][cc] = v.x;
            Bs[kq * 4 + 1][cc] = v.y;
            Bs[kq * 4 + 2][cc] = v.z;
            Bs[kq * 4 + 3][cc] = v.w;
        }
        __syncthreads();
#pragma unroll
        for (int kk = 0; kk < 16; kk++) {
            float a[4], b[4];
#pragma unroll
            for (int i = 0; i < 4; i++) a[i] = As[ty * 4 + i][kk];
#pragma unroll
            for (int j = 0; j < 4; j++) b[j] = Bs[kk][tx * 4 + j];
#pragma unroll
            for (int i = 0; i < 4; i++)
#pragma unroll
                for (int j = 0; j < 4; j++) acc[i][j] += a[i] * b[j];
        }
        __syncthreads();
    }
#pragma unroll
    for (int i = 0; i < 4; i++) {
        const int row = row0 + ty * 4 + i;
        float v[4];
#pragma unroll
        for (int j = 0; j < 4; j++) {
            const int col = c0 + tx * 4 + j;
            float val = acc[i][j] + lin_b[col];
            v[j] = val > 0.0f ? val : expm1f(val);
        }
        *(float4*)(out + (size_t)row * NEMBED + c0 + tx * 4) =
            make_float4(v[0], v[1], v[2], v[3]);
    }
}

extern "C" void kernel_launch(void* const* d_in, const int* in_sizes, int n_in,
                              void* d_out, int out_size, void* d_ws, size_t ws_size,
                              hipStream_t stream) {
    const float* x     = (const float*)d_in[0];
    const int*   adj   = (const int*)d_in[1];
    const float* W     = (const float*)d_in[2];
    const float* a_src = (const float*)d_in[3];
    const float* a_dst = (const float*)d_in[4];
    const float* lin_w = (const float*)d_in[5];
    const float* lin_b = (const float*)d_in[6];
    float* out = (float*)d_out;

    float* Wh   = (float*)d_ws;                                   // H*N*D = 1,572,864 f
    float* s    = Wh + (size_t)NHEADS * N_NODES * DHEAD;          // H*N   = 24,576 f
    float* t    = s + (size_t)NHEADS * N_NODES;                   // H*N
    float* hcat = t + (size_t)NHEADS * N_NODES;                   // N*NHID = 1,572,864 f

    wh_gemm<<<dim3(N_NODES / 64, NHEADS), 256, 0, stream>>>(x, W, Wh);
    st_kernel<<<N_NODES, 256, 0, stream>>>(Wh, a_src, a_dst, s, t);
    attn_agg<<<N_NODES, 256, 0, stream>>>(adj, Wh, s, t, hcat);
    out_gemm<<<dim3(N_NODES / 64, NEMBED / 64), 256, 0, stream>>>(hcat, lin_w, lin_b, out);
}

// Round 2
// 320.903 us; speedup vs baseline: 1.2074x; 1.2074x over previous
//
#include <hip/hip_runtime.h>
#include <hip/hip_bf16.h>
#include <math.h>

#define N_NODES 6144
#define NFEAT 512
#define NHID 256
#define NHEADS 4
#define DHEAD 64
#define NEMBED 128
#define LRELU_ALPHA 0.2f
#define MAXC 512   // p-buffer capacity per head; row degree ~Binom(6144,1%), max ~100

// ---------------------------------------------------------------------------
// Kernel 1: Wh[h][n][d] = sum_f x[n][f] * W[h][f][d]
// ---------------------------------------------------------------------------
__global__ __launch_bounds__(256) void wh_gemm(const float* __restrict__ x,
                                               const float* __restrict__ W,
                                               float* __restrict__ Wh) {
    __shared__ float As[64][16];
    __shared__ float Bs[16][64];
    const int tid = threadIdx.x;
    const int tx = tid & 15;
    const int ty = tid >> 4;
    const int row0 = blockIdx.x * 64;
    const int h = blockIdx.y;
    const float* Bp = W + (size_t)h * NFEAT * DHEAD;

    float acc[4][4] = {};

    for (int k0 = 0; k0 < NFEAT; k0 += 16) {
        {
            const int r = tid >> 2, kq = tid & 3;
            const float4 v = *(const float4*)(x + (size_t)(row0 + r) * NFEAT + k0 + kq * 4);
            *(float4*)&As[r][kq * 4] = v;
        }
        {
            const int kk = tid >> 4, cq = tid & 15;
            const float4 v = *(const float4*)(Bp + (size_t)(k0 + kk) * DHEAD + cq * 4);
            *(float4*)&Bs[kk][cq * 4] = v;
        }
        __syncthreads();
#pragma unroll
        for (int kk = 0; kk < 16; kk++) {
            float a[4], b[4];
#pragma unroll
            for (int i = 0; i < 4; i++) a[i] = As[ty * 4 + i][kk];
#pragma unroll
            for (int j = 0; j < 4; j++) b[j] = Bs[kk][tx * 4 + j];
#pragma unroll
            for (int i = 0; i < 4; i++)
#pragma unroll
                for (int j = 0; j < 4; j++) acc[i][j] += a[i] * b[j];
        }
        __syncthreads();
    }
#pragma unroll
    for (int i = 0; i < 4; i++) {
        const int row = row0 + ty * 4 + i;
        float4 v = make_float4(acc[i][0], acc[i][1], acc[i][2], acc[i][3]);
        *(float4*)(Wh + ((size_t)h * N_NODES + row) * DHEAD + tx * 4) = v;
    }
}

// ---------------------------------------------------------------------------
// Kernel 2: s/t per (head, node)
// ---------------------------------------------------------------------------
__global__ __launch_bounds__(256) void st_kernel(const float* __restrict__ Wh,
                                                 const float* __restrict__ a_src,
                                                 const float* __restrict__ a_dst,
                                                 float* __restrict__ s_arr,
                                                 float* __restrict__ t_arr) {
    const int n = blockIdx.x;
    const int h = threadIdx.x >> 6;
    const int lane = threadIdx.x & 63;
    const float wh = Wh[((size_t)h * N_NODES + n) * DHEAD + lane];
    float ps = wh * a_src[h * DHEAD + lane];
    float pt = wh * a_dst[h * DHEAD + lane];
#pragma unroll
    for (int off = 32; off > 0; off >>= 1) {
        ps += __shfl_down(ps, off);
        pt += __shfl_down(pt, off);
    }
    if (lane == 0) {
        s_arr[h * N_NODES + n] = ps;
        t_arr[h * N_NODES + n] = pt;
    }
}

// ---------------------------------------------------------------------------
// Kernel 3: per-row sparse attention. Block = dst node i; wave h = head h.
// Phase 1: int4 adj scan -> ushort neighbor list in LDS.
// Phase 2: lanes split neighbors; e -> LDS; wave max-reduce; parallel exp;
//          wave sum-reduce. (~1 exp per lane instead of c serial per wave.)
// Phase 3: acc[d] = sum_k p_k * Wh[j_k][d], 4-way unrolled gather.
// ---------------------------------------------------------------------------
__global__ __launch_bounds__(256) void attn_agg(const int* __restrict__ adj,
                                                const float* __restrict__ Wh,
                                                const float* __restrict__ s_arr,
                                                const float* __restrict__ t_arr,
                                                float* __restrict__ hcat) {
    __shared__ unsigned short nbr[N_NODES];
    __shared__ float p_s[NHEADS][MAXC];
    __shared__ int cnt;
    const int i = blockIdx.x;
    const int tid = threadIdx.x;
    if (tid == 0) cnt = 0;
    __syncthreads();

    // Phase 1: vectorized scan + compaction (order not preserved; softmax is
    // permutation-invariant up to FP rounding, margin is 12x threshold).
    const int* arow = adj + (size_t)i * N_NODES;
    for (int j0 = tid * 4; j0 < N_NODES; j0 += 1024) {
        const int4 v = *(const int4*)(arow + j0);
        if (v.x) nbr[atomicAdd(&cnt, 1)] = (unsigned short)(j0);
        if (v.y) nbr[atomicAdd(&cnt, 1)] = (unsigned short)(j0 + 1);
        if (v.z) nbr[atomicAdd(&cnt, 1)] = (unsigned short)(j0 + 2);
        if (v.w) nbr[atomicAdd(&cnt, 1)] = (unsigned short)(j0 + 3);
    }
    __syncthreads();
    const int c = cnt;

    const int h = tid >> 6;
    const int lane = tid & 63;
    const float s_h = s_arr[h * N_NODES + i];
    const float* tp = t_arr + (size_t)h * N_NODES;
    const float* whp = Wh + (size_t)h * N_NODES * DHEAD;

    float acc, l;
    if (c > 0 && c <= MAXC) {
        // Phase 2a: e_k into LDS, local max
        float m = -INFINITY;
        for (int k = lane; k < c; k += 64) {
            float e = s_h + tp[nbr[k]];
            e = e >= 0.0f ? e : LRELU_ALPHA * e;
            p_s[h][k] = e;
            m = fmaxf(m, e);
        }
#pragma unroll
        for (int off = 32; off > 0; off >>= 1) m = fmaxf(m, __shfl_xor(m, off));
        // Phase 2b: parallel exp, local sum
        float ls = 0.0f;
        for (int k = lane; k < c; k += 64) {
            const float p = __expf(p_s[h][k] - m);
            p_s[h][k] = p;
            ls += p;
        }
#pragma unroll
        for (int off = 32; off > 0; off >>= 1) ls += __shfl_xor(ls, off);
        l = ls;
        __syncthreads();   // p_s visible to whole wave (and safe vs other heads' reuse)

        // Phase 3: gather-aggregate, 4 independent accumulators
        float a0 = 0.0f, a1 = 0.0f, a2 = 0.0f, a3 = 0.0f;
        int k = 0;
        for (; k + 4 <= c; k += 4) {
            const int j0 = nbr[k], j1 = nbr[k + 1], j2 = nbr[k + 2], j3 = nbr[k + 3];
            const float p0 = p_s[h][k], p1 = p_s[h][k + 1],
                        p2 = p_s[h][k + 2], p3 = p_s[h][k + 3];
            a0 += p0 * whp[(size_t)j0 * DHEAD + lane];
            a1 += p1 * whp[(size_t)j1 * DHEAD + lane];
            a2 += p2 * whp[(size_t)j2 * DHEAD + lane];
            a3 += p3 * whp[(size_t)j3 * DHEAD + lane];
        }
        for (; k < c; k++) a0 += p_s[h][k] * whp[(size_t)nbr[k] * DHEAD + lane];
        acc = (a0 + a1) + (a2 + a3);
    } else if (c == 0) {
        // all logits NEG_INF -> uniform softmax over all nodes
        acc = 0.0f;
        for (int j = 0; j < N_NODES; j++) acc += whp[(size_t)j * DHEAD + lane];
        l = (float)N_NODES;
    } else {
        // c > MAXC fallback: serial online softmax (never expected at 1% density)
        float m = -INFINITY, ll = 0.0f;
        acc = 0.0f;
        for (int k = 0; k < c; k++) {
            const int j = nbr[k];
            float e = s_h + tp[j];
            e = e >= 0.0f ? e : LRELU_ALPHA * e;
            const float m_new = fmaxf(m, e);
            const float scale = expf(m - m_new);
            const float p = expf(e - m_new);
            ll = ll * scale + p;
            acc = acc * scale + p * whp[(size_t)j * DHEAD + lane];
            m = m_new;
        }
        l = ll;
    }
    float hv = acc / l;
    hv = hv > 0.0f ? hv : expm1f(hv);
    hcat[(size_t)i * NHID + h * DHEAD + lane] = hv;
}

// ---------------------------------------------------------------------------
// Kernel 4: out = elu(hcat @ lin_w^T + b)
// ---------------------------------------------------------------------------
__global__ __launch_bounds__(256) void out_gemm(const float* __restrict__ hcat,
                                                const float* __restrict__ lin_w,
                                                const float* __restrict__ lin_b,
                                                float* __restrict__ out) {
    __shared__ float As[64][16];
    __shared__ float Bs[16][64];
    const int tid = threadIdx.x;
    const int tx = tid & 15;
    const int ty = tid >> 4;
    const int row0 = blockIdx.x * 64;
    const int c0 = blockIdx.y * 64;

    float acc[4][4] = {};

    for (int k0 = 0; k0 < NHID; k0 += 16) {
        {
            const int r = tid >> 2, kq = tid & 3;
            const float4 v = *(const float4*)(hcat + (size_t)(row0 + r) * NHID + k0 + kq * 4);
            *(float4*)&As[r][kq * 4] = v;
        }
        {
            const int cc = tid & 63, kq = tid >> 6;
            const float4 v = *(const float4*)(lin_w + (size_t)(c0 + cc) * NHID + k0 + kq * 4);
            Bs[kq * 4 + 0][cc] = v.x;
            Bs[kq * 4 + 1][cc] = v.y;
            Bs[kq * 4 + 2][cc] = v.z;
            Bs[kq * 4 + 3][cc] = v.w;
        }
        __syncthreads();
#pragma unroll
        for (int kk = 0; kk < 16; kk++) {
            float a[4], b[4];
#pragma unroll
            for (int i = 0; i < 4; i++) a[i] = As[ty * 4 + i][kk];
#pragma unroll
            for (int j = 0; j < 4; j++) b[j] = Bs[kk][tx * 4 + j];
#pragma unroll
            for (int i = 0; i < 4; i++)
#pragma unroll
                for (int j = 0; j < 4; j++) acc[i][j] += a[i] * b[j];
        }
        __syncthreads();
    }
#pragma unroll
    for (int i = 0; i < 4; i++) {
        const int row = row0 + ty * 4 + i;
        float v[4];
#pragma unroll
        for (int j = 0; j < 4; j++) {
            const int col = c0 + tx * 4 + j;
            float val = acc[i][j] + lin_b[col];
            v[j] = val > 0.0f ? val : expm1f(val);
        }
        *(float4*)(out + (size_t)row * NEMBED + c0 + tx * 4) =
            make_float4(v[0], v[1], v[2], v[3]);
    }
}

extern "C" void kernel_launch(void* const* d_in, const int* in_sizes, int n_in,
                              void* d_out, int out_size, void* d_ws, size_t ws_size,
                              hipStream_t stream) {
    const float* x     = (const float*)d_in[0];
    const int*   adj   = (const int*)d_in[1];
    const float* W     = (const float*)d_in[2];
    const float* a_src = (const float*)d_in[3];
    const float* a_dst = (const float*)d_in[4];
    const float* lin_w = (const float*)d_in[5];
    const float* lin_b = (const float*)d_in[6];
    float* out = (float*)d_out;

    float* Wh   = (float*)d_ws;
    float* s    = Wh + (size_t)NHEADS * N_NODES * DHEAD;
    float* t    = s + (size_t)NHEADS * N_NODES;
    float* hcat = t + (size_t)NHEADS * N_NODES;

    wh_gemm<<<dim3(N_NODES / 64, NHEADS), 256, 0, stream>>>(x, W, Wh);
    st_kernel<<<N_NODES, 256, 0, stream>>>(Wh, a_src, a_dst, s, t);
    attn_agg<<<N_NODES, 256, 0, stream>>>(adj, Wh, s, t, hcat);
    out_gemm<<<dim3(N_NODES / 64, NEMBED / 64), 256, 0, stream>>>(hcat, lin_w, lin_b, out);
}

// Round 3
// 308.000 us; speedup vs baseline: 1.2580x; 1.0419x over previous
//
#include <hip/hip_runtime.h>
#include <hip/hip_bf16.h>
#include <math.h>

#define N_NODES 6144
#define NFEAT 512
#define NHID 256
#define NHEADS 4
#define DHEAD 64
#define NEMBED 128
#define LRELU_ALPHA 0.2f
#define MAXC 256   // p-buffer capacity/head; degree ~Binom(6144,1%): mean 61, max~100

// ---------------------------------------------------------------------------
// Kernel 1: Wh[h][n][d] = sum_f x[n][f] * W[h][f][d]; fused epilogue computes
// s[h][n] = Wh[h][n][:].a_src[h], t likewise (block holds the full DHEAD tile).
// ---------------------------------------------------------------------------
__global__ __launch_bounds__(256) void wh_gemm(const float* __restrict__ x,
                                               const float* __restrict__ W,
                                               const float* __restrict__ a_src,
                                               const float* __restrict__ a_dst,
                                               float* __restrict__ Wh,
                                               float* __restrict__ s_arr,
                                               float* __restrict__ t_arr) {
    __shared__ float As[64][16];
    __shared__ float Bs[16][64];
    const int tid = threadIdx.x;
    const int tx = tid & 15;
    const int ty = tid >> 4;
    const int row0 = blockIdx.x * 64;
    const int h = blockIdx.y;
    const float* Bp = W + (size_t)h * NFEAT * DHEAD;

    float acc[4][4] = {};

    for (int k0 = 0; k0 < NFEAT; k0 += 16) {
        {
            const int r = tid >> 2, kq = tid & 3;
            const float4 v = *(const float4*)(x + (size_t)(row0 + r) * NFEAT + k0 + kq * 4);
            *(float4*)&As[r][kq * 4] = v;
        }
        {
            const int kk = tid >> 4, cq = tid & 15;
            const float4 v = *(const float4*)(Bp + (size_t)(k0 + kk) * DHEAD + cq * 4);
            *(float4*)&Bs[kk][cq * 4] = v;
        }
        __syncthreads();
#pragma unroll
        for (int kk = 0; kk < 16; kk++) {
            float a[4], b[4];
#pragma unroll
            for (int i = 0; i < 4; i++) a[i] = As[ty * 4 + i][kk];
#pragma unroll
            for (int j = 0; j < 4; j++) b[j] = Bs[kk][tx * 4 + j];
#pragma unroll
            for (int i = 0; i < 4; i++)
#pragma unroll
                for (int j = 0; j < 4; j++) acc[i][j] += a[i] * b[j];
        }
        __syncthreads();
    }
    // store Wh
#pragma unroll
    for (int i = 0; i < 4; i++) {
        const int row = row0 + ty * 4 + i;
        float4 v = make_float4(acc[i][0], acc[i][1], acc[i][2], acc[i][3]);
        *(float4*)(Wh + ((size_t)h * N_NODES + row) * DHEAD + tx * 4) = v;
    }
    // fused s/t: per-thread partial over its 4 cols, then 16-lane xor-reduce
    float a4s[4], a4d[4];
#pragma unroll
    for (int j = 0; j < 4; j++) {
        a4s[j] = a_src[h * DHEAD + tx * 4 + j];
        a4d[j] = a_dst[h * DHEAD + tx * 4 + j];
    }
#pragma unroll
    for (int i = 0; i < 4; i++) {
        float ps = acc[i][0] * a4s[0] + acc[i][1] * a4s[1] +
                   acc[i][2] * a4s[2] + acc[i][3] * a4s[3];
        float pt = acc[i][0] * a4d[0] + acc[i][1] * a4d[1] +
                   acc[i][2] * a4d[2] + acc[i][3] * a4d[3];
#pragma unroll
        for (int off = 1; off < 16; off <<= 1) {
            ps += __shfl_xor(ps, off);
            pt += __shfl_xor(pt, off);
        }
        if (tx == 0) {
            const int row = row0 + ty * 4 + i;
            s_arr[h * N_NODES + row] = ps;
            t_arr[h * N_NODES + row] = pt;
        }
    }
}

// ---------------------------------------------------------------------------
// Kernel 2: per-row sparse attention. Block = dst node i; wave h = head h.
// Phase 1: int4 adj scan -> ballot/popcount wave compaction (1 atomic/wave/iter).
// Phase 2: parallel softmax over neighbors (e in LDS, wave reduce, ~1 exp/lane).
// Phase 3: acc[d] = sum_k p_k * Wh[j_k][d], 8 independent gathers in flight.
// LDS ~16.5 KB -> 8 blocks/CU (thread-capped), ~100% occupancy.
// ---------------------------------------------------------------------------
__global__ __launch_bounds__(256) void attn_agg(const int* __restrict__ adj,
                                                const float* __restrict__ Wh,
                                                const float* __restrict__ s_arr,
                                                const float* __restrict__ t_arr,
                                                float* __restrict__ hcat) {
    __shared__ unsigned short nbr[N_NODES];
    __shared__ float p_s[NHEADS][MAXC];
    __shared__ int cnt;
    const int i = blockIdx.x;
    const int tid = threadIdx.x;
    const int wid = tid >> 6;
    const int lane = tid & 63;
    if (tid == 0) cnt = 0;
    __syncthreads();

    // Phase 1: ballot compaction (wave-ordered; neighbor order is irrelevant to
    // softmax up to FP rounding — margin is 6x threshold).
    const int* arow = adj + (size_t)i * N_NODES;
    const unsigned long long lower = (1ull << lane) - 1ull;
#pragma unroll
    for (int it = 0; it < 6; ++it) {
        const int j0 = it * 1024 + wid * 256 + lane * 4;
        const int4 v = *(const int4*)(arow + j0);
        const unsigned long long b0 = __ballot(v.x != 0);
        const unsigned long long b1 = __ballot(v.y != 0);
        const unsigned long long b2 = __ballot(v.z != 0);
        const unsigned long long b3 = __ballot(v.w != 0);
        const int n0 = __popcll(b0), n1 = __popcll(b1);
        const int n2 = __popcll(b2), n3 = __popcll(b3);
        const int tot = n0 + n1 + n2 + n3;
        int base = 0;
        if (lane == 0 && tot) base = atomicAdd(&cnt, tot);
        base = __shfl(base, 0);
        if (v.x) nbr[base + __popcll(b0 & lower)] = (unsigned short)j0;
        base += n0;
        if (v.y) nbr[base + __popcll(b1 & lower)] = (unsigned short)(j0 + 1);
        base += n1;
        if (v.z) nbr[base + __popcll(b2 & lower)] = (unsigned short)(j0 + 2);
        base += n2;
        if (v.w) nbr[base + __popcll(b3 & lower)] = (unsigned short)(j0 + 3);
    }
    __syncthreads();
    const int c = cnt;

    const int h = wid;
    const float s_h = s_arr[h * N_NODES + i];
    const float* tp = t_arr + (size_t)h * N_NODES;
    const float* whp = Wh + (size_t)h * N_NODES * DHEAD;

    float acc, l;
    if (c > 0 && c <= MAXC) {
        // Phase 2a: e_k into LDS, wave max
        float m = -INFINITY;
        for (int k = lane; k < c; k += 64) {
            float e = s_h + tp[nbr[k]];
            e = e >= 0.0f ? e : LRELU_ALPHA * e;
            p_s[h][k] = e;
            m = fmaxf(m, e);
        }
#pragma unroll
        for (int off = 32; off > 0; off >>= 1) m = fmaxf(m, __shfl_xor(m, off));
        // Phase 2b: parallel exp, wave sum
        float ls = 0.0f;
        for (int k = lane; k < c; k += 64) {
            const float p = __expf(p_s[h][k] - m);
            p_s[h][k] = p;
            ls += p;
        }
#pragma unroll
        for (int off = 32; off > 0; off >>= 1) ls += __shfl_xor(ls, off);
        l = ls;
        // p_s is wave-private (head h written/read only by wave h): no barrier.

        // Phase 3: gather-aggregate, 8 independent loads in flight
        float a0 = 0.f, a1 = 0.f, a2 = 0.f, a3 = 0.f;
        float a4 = 0.f, a5 = 0.f, a6 = 0.f, a7 = 0.f;
        int k = 0;
        for (; k + 8 <= c; k += 8) {
            const int j0 = nbr[k],     j1 = nbr[k + 1], j2 = nbr[k + 2], j3 = nbr[k + 3];
            const int j4 = nbr[k + 4], j5 = nbr[k + 5], j6 = nbr[k + 6], j7 = nbr[k + 7];
            const float p0 = p_s[h][k],     p1 = p_s[h][k + 1];
            const float p2 = p_s[h][k + 2], p3 = p_s[h][k + 3];
            const float p4 = p_s[h][k + 4], p5 = p_s[h][k + 5];
            const float p6 = p_s[h][k + 6], p7 = p_s[h][k + 7];
            a0 += p0 * whp[(size_t)j0 * DHEAD + lane];
            a1 += p1 * whp[(size_t)j1 * DHEAD + lane];
            a2 += p2 * whp[(size_t)j2 * DHEAD + lane];
            a3 += p3 * whp[(size_t)j3 * DHEAD + lane];
            a4 += p4 * whp[(size_t)j4 * DHEAD + lane];
            a5 += p5 * whp[(size_t)j5 * DHEAD + lane];
            a6 += p6 * whp[(size_t)j6 * DHEAD + lane];
            a7 += p7 * whp[(size_t)j7 * DHEAD + lane];
        }
        for (; k < c; k++) a0 += p_s[h][k] * whp[(size_t)nbr[k] * DHEAD + lane];
        acc = ((a0 + a1) + (a2 + a3)) + ((a4 + a5) + (a6 + a7));
    } else if (c == 0) {
        // all logits NEG_INF -> uniform softmax over all nodes
        acc = 0.0f;
        for (int j = 0; j < N_NODES; j++) acc += whp[(size_t)j * DHEAD + lane];
        l = (float)N_NODES;
    } else {
        // c > MAXC fallback: serial online softmax (not expected at 1% density)
        float m = -INFINITY, ll = 0.0f;
        acc = 0.0f;
        for (int k = 0; k < c; k++) {
            const int j = nbr[k];
            float e = s_h + tp[j];
            e = e >= 0.0f ? e : LRELU_ALPHA * e;
            const float m_new = fmaxf(m, e);
            const float scale = __expf(m - m_new);
            const float p = __expf(e - m_new);
            ll = ll * scale + p;
            acc = acc * scale + p * whp[(size_t)j * DHEAD + lane];
            m = m_new;
        }
        l = ll;
    }
    float hv = acc / l;
    hv = hv > 0.0f ? hv : expm1f(hv);
    hcat[(size_t)i * NHID + h * DHEAD + lane] = hv;
}

// ---------------------------------------------------------------------------
// Kernel 3: out = elu(hcat @ lin_w^T + b)
// ---------------------------------------------------------------------------
__global__ __launch_bounds__(256) void out_gemm(const float* __restrict__ hcat,
                                                const float* __restrict__ lin_w,
                                                const float* __restrict__ lin_b,
                                                float* __restrict__ out) {
    __shared__ float As[64][16];
    __shared__ float Bs[16][64];
    const int tid = threadIdx.x;
    const int tx = tid & 15;
    const int ty = tid >> 4;
    const int row0 = blockIdx.x * 64;
    const int c0 = blockIdx.y * 64;

    float acc[4][4] = {};

    for (int k0 = 0; k0 < NHID; k0 += 16) {
        {
            const int r = tid >> 2, kq = tid & 3;
            const float4 v = *(const float4*)(hcat + (size_t)(row0 + r) * NHID + k0 + kq * 4);
            *(float4*)&As[r][kq * 4] = v;
        }
        {
            const int cc = tid & 63, kq = tid >> 6;
            const float4 v = *(const float4*)(lin_w + (size_t)(c0 + cc) * NHID + k0 + kq * 4);
            Bs[kq * 4 + 0][cc] = v.x;
            Bs[kq * 4 + 1][cc] = v.y;
            Bs[kq * 4 + 2][cc] = v.z;
            Bs[kq * 4 + 3][cc] = v.w;
        }
        __syncthreads();
#pragma unroll
        for (int kk = 0; kk < 16; kk++) {
            float a[4], b[4];
#pragma unroll
            for (int i = 0; i < 4; i++) a[i] = As[ty * 4 + i][kk];
#pragma unroll
            for (int j = 0; j < 4; j++) b[j] = Bs[kk][tx * 4 + j];
#pragma unroll
            for (int i = 0; i < 4; i++)
#pragma unroll
                for (int j = 0; j < 4; j++) acc[i][j] += a[i] * b[j];
        }
        __syncthreads();
    }
#pragma unroll
    for (int i = 0; i < 4; i++) {
        const int row = row0 + ty * 4 + i;
        float v[4];
#pragma unroll
        for (int j = 0; j < 4; j++) {
            const int col = c0 + tx * 4 + j;
            float val = acc[i][j] + lin_b[col];
            v[j] = val > 0.0f ? val : expm1f(val);
        }
        *(float4*)(out + (size_t)row * NEMBED + c0 + tx * 4) =
            make_float4(v[0], v[1], v[2], v[3]);
    }
}

extern "C" void kernel_launch(void* const* d_in, const int* in_sizes, int n_in,
                              void* d_out, int out_size, void* d_ws, size_t ws_size,
                              hipStream_t stream) {
    const float* x     = (const float*)d_in[0];
    const int*   adj   = (const int*)d_in[1];
    const float* W     = (const float*)d_in[2];
    const float* a_src = (const float*)d_in[3];
    const float* a_dst = (const float*)d_in[4];
    const float* lin_w = (const float*)d_in[5];
    const float* lin_b = (const float*)d_in[6];
    float* out = (float*)d_out;

    float* Wh   = (float*)d_ws;
    float* s    = Wh + (size_t)NHEADS * N_NODES * DHEAD;
    float* t    = s + (size_t)NHEADS * N_NODES;
    float* hcat = t + (size_t)NHEADS * N_NODES;

    wh_gemm<<<dim3(N_NODES / 64, NHEADS), 256, 0, stream>>>(x, W, a_src, a_dst, Wh, s, t);
    attn_agg<<<N_NODES, 256, 0, stream>>>(adj, Wh, s, t, hcat);
    out_gemm<<<dim3(N_NODES / 64, NEMBED / 64), 256, 0, stream>>>(hcat, lin_w, lin_b, out);
}